// Round 1
// baseline (259.623 us; speedup 1.0000x reference)
//
#include <hip/hip_runtime.h>
#include <hip/hip_bf16.h>
#include <stdint.h>

#define AS1 __attribute__((address_space(1)))
#define AS3 __attribute__((address_space(3)))

typedef __bf16 bf16x8 __attribute__((ext_vector_type(8)));
typedef __bf16 bf16x4 __attribute__((ext_vector_type(4)));
typedef float  floatx4 __attribute__((ext_vector_type(4)));

static constexpr int NB   = 512;            // batch
static constexpr int LL   = 257;            // seq len (feat)
static constexpr int HH   = 256;            // feature dim
static constexpr int M    = NB * (LL - 1);  // 131072 rows
static constexpr int K1   = 2 * HH;         // 512  (concat dim)
static constexpr int NHID = 256;            // hidden
static constexpr int NLAB = 50;             // labels

// async global->LDS, 16B per lane. LDS side MUST be wave-uniform base + lane*16.
__device__ __forceinline__ void async16(const void* gptr, void* ldsptr) {
  __builtin_amdgcn_global_load_lds((const AS1 void*)gptr, (AS3 void*)ldsptr, 16, 0, 0);
}

// ---------------- prep: W1,W2 -> bf16 in workspace ----------------
// w1b: [256][512] bf16 ; w2b: [64][256] bf16 (rows 50..63 zero)
__global__ void prep_w(const float* __restrict__ W1, const float* __restrict__ W2,
                       __bf16* __restrict__ w1b, __bf16* __restrict__ w2b) {
  int idx = blockIdx.x * 256 + threadIdx.x;   // one thread per 8 elements
  if (idx < 16384) {                          // W1: 131072 / 8
    const float4* s = (const float4*)(W1 + (size_t)idx * 8);
    float4 a = s[0], b = s[1];
    bf16x8 v;
    v[0]=(__bf16)a.x; v[1]=(__bf16)a.y; v[2]=(__bf16)a.z; v[3]=(__bf16)a.w;
    v[4]=(__bf16)b.x; v[5]=(__bf16)b.y; v[6]=(__bf16)b.z; v[7]=(__bf16)b.w;
    *(bf16x8*)(w1b + (size_t)idx * 8) = v;
  } else {                                    // W2 padded: 64*256/8 = 2048 chunks
    int j = idx - 16384;
    int row = j >> 5;                         // 0..63
    int col = (j & 31) * 8;
    float4 a = {0.f,0.f,0.f,0.f}, b = {0.f,0.f,0.f,0.f};
    if (row < NLAB) {
      const float4* s = (const float4*)(W2 + (size_t)row * 256 + col);
      a = s[0]; b = s[1];
    }
    bf16x8 v;
    v[0]=(__bf16)a.x; v[1]=(__bf16)a.y; v[2]=(__bf16)a.z; v[3]=(__bf16)a.w;
    v[4]=(__bf16)b.x; v[5]=(__bf16)b.y; v[6]=(__bf16)b.z; v[7]=(__bf16)b.w;
    *(bf16x8*)(w2b + (size_t)j * 8) = v;
  }
}

// ---------------- fused gather + MLP ----------------
// Per block: 64 rows of M. Stage1: hid[64][256] = relu(W1 * cat^T + b1) via MFMA
// (A = W1 so C-layout rows are the hidden dim -> b64 LDS writes, float4 bias).
// Stage2: out[64][50] = hid * W2^T + b2.
__global__ __launch_bounds__(256, 2)
void fused_kernel(const float* __restrict__ feat, const int* __restrict__ heads,
                  const __bf16* __restrict__ w1b, const float* __restrict__ b1,
                  const __bf16* __restrict__ w2b, const float* __restrict__ b2,
                  float* __restrict__ out) {
  // LDS: [0,8K) catS fp32 [64][32] | [8K,24K) W1s bf16 [256][32]  (stage 1)
  //      [0,32K) hidS bf16 [64][256] swizzled (stage 2, aliases stage-1 bufs)
  //      [32K,64K) W2s bf16 [64][256] swizzled (resident whole kernel)
  __shared__ __align__(16) char smem[65536];
  float*  catS = (float*)smem;
  __bf16* W1s  = (__bf16*)(smem + 8192);
  __bf16* hidS = (__bf16*)smem;
  __bf16* W2s  = (__bf16*)(smem + 32768);

  const int t    = threadIdx.x;
  const int w    = t >> 6;        // wave 0..3
  const int lane = t & 63;
  const int lr   = lane & 15;
  const int q    = lane >> 4;     // quad 0..3
  const int mBase = blockIdx.x * 64;

  // ---- load W2 into LDS, XOR-swizzled: position p holds global chunk p^(row&7) ----
  #pragma unroll
  for (int i = 0; i < 8; ++i) {
    int c = t + i * 256;                  // 0..2047 chunks of 8 bf16
    int row = c >> 5, p = c & 31;
    int g = p ^ (row & 7);
    *(bf16x8*)(W2s + row * 256 + p * 8) =
        *(const bf16x8*)(w2b + (size_t)row * 256 + g * 8);
  }

  // ---- per-thread staging sources (constant over the K loop) ----
  // cat tile: 64 rows x 32 fp32 = 512 chunks of 16B; this thread owns chunks t, t+256.
  const int r0  = t >> 3;                 // row of chunk c=t (0..31); chunk t+256 -> r0+32
  const int gs  = (t & 7) ^ (r0 & 7);     // XOR-swizzled global sub-chunk (same for both rows)
  const int m0  = mBase + r0;
  const int m1  = m0 + 32;
  const float* bd0 = feat + ((size_t)((m0 >> 8) * LL + (m0 & 255) + 1)) * HH;
  const float* bh0 = feat + ((size_t)((m0 >> 8) * LL + heads[m0])) * HH;
  const float* bd1 = feat + ((size_t)((m1 >> 8) * LL + (m1 & 255) + 1)) * HH;
  const float* bh1 = feat + ((size_t)((m1 >> 8) * LL + heads[m1])) * HH;
  const int catOff = gs * 4;              // float offset inside the 32-float window

  // W1 tile: 256 rows x 32 bf16 = 1024 chunks; thread owns n0, n0+64, n0+128, n0+192
  const int n0 = t >> 2;
  const int gw = ((t & 3) ^ ((n0 >> 1) & 3)) * 8;   // swizzled elem offset (same all 4 rows)

  floatx4 acc[4][4];
  #pragma unroll
  for (int i = 0; i < 4; ++i)
    #pragma unroll
    for (int j = 0; j < 4; ++j)
      acc[i][j] = (floatx4){0.f, 0.f, 0.f, 0.f};

  const int posw = (q ^ ((lr >> 1) & 3)) * 8;   // W1s read chunk (swizzle-matched)
  const int pc0  = (2 * q) ^ (lr & 7);          // catS read chunks (fp32, 2 per frag)
  const int pc1  = pc0 ^ 1;

  // ---------------- stage 1 K loop: 16 steps of BK=32 ----------------
  for (int kt = 0; kt < 16; ++kt) {
    const int k0 = kt * 32;
    __syncthreads();
    {
      const float* s0 = (kt < 8) ? bd0 : bh0;   // first 256 cols: dependent, rest: head
      const float* s1 = (kt < 8) ? bd1 : bh1;
      const int kk = k0 & 255;
      async16(s0 + kk + catOff, catS + t * 4);
      async16(s1 + kk + catOff, catS + (t + 256) * 4);
      const __bf16* wsrc = w1b + k0 + gw;
      async16(wsrc + (size_t)n0 * K1,         W1s + t * 8);
      async16(wsrc + (size_t)(n0 + 64) * K1,  W1s + (t + 256) * 8);
      async16(wsrc + (size_t)(n0 + 128) * K1, W1s + (t + 512) * 8);
      async16(wsrc + (size_t)(n0 + 192) * K1, W1s + (t + 768) * 8);
    }
    __syncthreads();

    bf16x8 af[4], bb[4];
    #pragma unroll
    for (int oi = 0; oi < 4; ++oi) {
      const int o = w * 64 + oi * 16 + lr;
      af[oi] = *(const bf16x8*)(W1s + o * 32 + posw);
    }
    #pragma unroll
    for (int mi = 0; mi < 4; ++mi) {
      const int m = mi * 16 + lr;
      float4 fa = *(const float4*)(catS + m * 32 + pc0 * 4);
      float4 fb = *(const float4*)(catS + m * 32 + pc1 * 4);
      bf16x8 vv;
      vv[0]=(__bf16)fa.x; vv[1]=(__bf16)fa.y; vv[2]=(__bf16)fa.z; vv[3]=(__bf16)fa.w;
      vv[4]=(__bf16)fb.x; vv[5]=(__bf16)fb.y; vv[6]=(__bf16)fb.z; vv[7]=(__bf16)fb.w;
      bb[mi] = vv;
    }
    #pragma unroll
    for (int oi = 0; oi < 4; ++oi)
      #pragma unroll
      for (int mi = 0; mi < 4; ++mi)
        acc[oi][mi] = __builtin_amdgcn_mfma_f32_16x16x32_bf16(af[oi], bb[mi], acc[oi][mi], 0, 0, 0);
  }

  __syncthreads();   // everyone done reading catS/W1s before hidS overwrites them

  // ---- stage-1 epilogue: bias + relu, write hid tile (bf16, swizzled) ----
  // C-layout: row(in-tile) = hidden o = q*4+r, col = m = lr  -> b64 quads along o.
  float4 biasv[4];
  #pragma unroll
  for (int oi = 0; oi < 4; ++oi)
    biasv[oi] = *(const float4*)(b1 + w * 64 + oi * 16 + q * 4);

  #pragma unroll
  for (int mi = 0; mi < 4; ++mi) {
    const int m = mi * 16 + lr;
    const int s = lr & 7;
    #pragma unroll
    for (int oi = 0; oi < 4; ++oi) {
      const int j = w * 8 + oi * 2 + (q >> 1);      // o-octet index
      bf16x4 hv;
      const float* bp = (const float*)&biasv[oi];
      #pragma unroll
      for (int r = 0; r < 4; ++r) {
        float v = acc[oi][mi][r] + bp[r];
        v = v > 0.f ? v : 0.f;
        hv[r] = (__bf16)v;
      }
      *(bf16x4*)(hidS + m * 256 + ((j ^ s) << 3) + (q & 1) * 4) = hv;
    }
  }
  __syncthreads();

  // ---------------- stage 2: out = hid * W2^T + b2 ----------------
  // wave w owns rows [w*16, w*16+16); A-operand m = lr, k = q*8+j.
  floatx4 acc2[4];
  #pragma unroll
  for (int i = 0; i < 4; ++i) acc2[i] = (floatx4){0.f, 0.f, 0.f, 0.f};

  const int m2 = w * 16 + lr;
  const int s2 = lr & 7;
  #pragma unroll
  for (int kt2 = 0; kt2 < 8; ++kt2) {
    const int gc = kt2 * 4 + q;                      // global 8-elem chunk of k
    bf16x8 a2 = *(const bf16x8*)(hidS + m2 * 256 + ((gc ^ s2) << 3));
    #pragma unroll
    for (int ni = 0; ni < 4; ++ni) {
      const int n = ni * 16 + lr;
      bf16x8 b2f = *(const bf16x8*)(W2s + n * 256 + ((gc ^ (lr & 7)) << 3));
      acc2[ni] = __builtin_amdgcn_mfma_f32_16x16x32_bf16(a2, b2f, acc2[ni], 0, 0, 0);
    }
  }

  const int rowBase = mBase + w * 16 + q * 4;
  #pragma unroll
  for (int ni = 0; ni < 4; ++ni) {
    const int col = ni * 16 + lr;
    if (col < NLAB) {
      const float bias = b2[col];
      #pragma unroll
      for (int r = 0; r < 4; ++r)
        out[(size_t)(rowBase + r) * NLAB + col] = acc2[ni][r] + bias;
    }
  }
}

extern "C" void kernel_launch(void* const* d_in, const int* in_sizes, int n_in,
                              void* d_out, int out_size, void* d_ws, size_t ws_size,
                              hipStream_t stream) {
  const float* feat  = (const float*)d_in[0];
  const int*   heads = (const int*)d_in[1];
  // d_in[2] = masks (all ones, unused by the reference output)
  const float* W1 = (const float*)d_in[3];
  const float* b1 = (const float*)d_in[4];
  const float* W2 = (const float*)d_in[5];
  const float* b2 = (const float*)d_in[6];
  float* out = (float*)d_out;

  __bf16* w1b = (__bf16*)d_ws;             // 256*512 bf16 = 256 KB
  __bf16* w2b = w1b + 256 * 512;           // 64*256 bf16 = 32 KB (total ws use: 288 KB)

  prep_w<<<72, 256, 0, stream>>>(W1, W2, w1b, w2b);
  fused_kernel<<<M / 64, 256, 0, stream>>>(feat, heads, w1b, b1, w2b, b2, out);
}